// Round 12
// baseline (79.252 us; speedup 1.0000x reference)
//
#include <hip/hip_runtime.h>
#include <hip/hip_cooperative_groups.h>
#include <math.h>

namespace cg = cooperative_groups;

#define NN 320
#define DFULL 129            // 1 time dim + 128 spatial
#define MIN_DIST_F 0.1f
#define MARGIN_F 0.1f
#define WEIGHT_F 0.1f
#define NT2 10               // 320/32 supertiles per dim
#define NTRI2 55             // triangular supertiles
#define GBLK 256             // blocks (1 per CU, cooperative-resident)
#define TBLK 1024            // threads/block = 16 waves = 4 waves/SIMD
#define NUNIT 8320           // 320 anchors * 26 triangle-pruned (kg,jc40) chunks
#define NWAVES (GBLK*(TBLK/64))  // 4096

__device__ __forceinline__ int tri2_off(int a) { return a * NT2 - (a * (a - 1)) / 2; }

// Single cooperative kernel: Phase1 Gram+poison -> sync -> Phase2 loss -> sync -> Phase3 out.
__global__ __launch_bounds__(TBLK) void coop_kernel(const float* __restrict__ E,
                                                    const float* __restrict__ gt,
                                                    float* __restrict__ embp,
                                                    float2* __restrict__ partial,
                                                    float* __restrict__ out) {
    const int b = blockIdx.x;
    const int t = threadIdx.x;
    const int lane = t & 63, wid = t >> 6;

    __shared__ float As[32][DFULL];
    __shared__ float Bs[32][DFULL];
    __shared__ float wt[TBLK / 64];
    __shared__ int   wc[TBLK / 64];

    // ---- Phase 1: Lorentz distances, NaN-poisoned, symmetric (r5 math, 32x32 supertiles) ----
    if (b < NTRI2) {
        float fa = (2.0f * NT2 + 1.0f - sqrtf((2.0f*NT2+1.0f)*(2.0f*NT2+1.0f) - 8.0f * (float)b)) * 0.5f;
        int a = (int)fa;
        if (a > 0 && tri2_off(a) > b) --a;
        if (tri2_off(a + 1) <= b) ++a;
        const int bb = a + (b - tri2_off(a));
        const int i0 = a * 32, j0 = bb * 32;

        for (int q = t; q < 32 * DFULL; q += TBLK) {
            int r = q / DFULL, c = q - r * DFULL;
            As[r][c] = E[(i0 + r) * DFULL + c];
            Bs[r][c] = E[(j0 + r) * DFULL + c];
        }
        __syncthreads();
        const int tj = t >> 5, ti = t & 31;
        const int i = i0 + tj, j = j0 + ti;
        float tt = As[tj][0] * Bs[ti][0];    // [32][129]: bank (ti+d)%32 -> conflict-free
        float ss = 0.0f;
        #pragma unroll
        for (int d = 1; d < DFULL; ++d) ss = fmaf(As[tj][d], Bs[ti][d], ss);
        float x = fmaxf(tt - ss, 1.0f + 1e-7f);
        float e = acoshf(x);
        float g = gt[i * NN + j];
        float ep = (g >= MIN_DIST_F && i != j) ? e : __builtin_nanf("");
        embp[i * NN + j] = ep;
        if (a != bb) embp[j * NN + i] = ep;  // gt exactly symmetric; e bitwise-symmetric
    }
    cg::this_grid().sync();

    // ---- Phase 2: triangle loss; unit = (anchor i, chunk c of 26), one wave per unit ----
    // chunk c -> (kg, jc): kg0:jc0-7 | kg1:jc1-7 | kg2:jc3-7 | kg3:jc4-7 | kg4:jc6-7
    // lane owns k = kg*64+lane; j sweeps [40jc, 40jc+40) masked j>k (exact triu).
    // NaN-poisoned embp: v NaN -> (v>0) false -> cndmask adds 0 (never mult-by-flag).
    float tot = 0.0f;
    int   cnt = 0;
    const int w = b * (TBLK / 64) + wid;
    for (int u = w; u < NUNIT; u += NWAVES) {
        const int i = u / 26;
        const int c = u - i * 26;
        int kg, jc;
        if      (c <  8) { kg = 0; jc = c;      }
        else if (c < 15) { kg = 1; jc = c - 7;  }
        else if (c < 20) { kg = 2; jc = c - 12; }
        else if (c < 24) { kg = 3; jc = c - 16; }
        else             { kg = 4; jc = c - 18; }
        const int k  = (kg << 6) + lane;
        const int j0 = jc * 40;
        const float* __restrict__ erow = embp + i * NN;
        const float* __restrict__ grow = gt   + i * NN;
        const float ek = erow[k];
        const float gk = grow[k];
        #pragma unroll
        for (int jb = 0; jb < 40; jb += 4) {
            const float4 e4 = *reinterpret_cast<const float4*>(erow + j0 + jb);
            const float4 g4 = *reinterpret_cast<const float4*>(grow + j0 + jb);
            {   const int j = j0 + jb;
                float d = gk - g4.x; float v = fmaf(copysignf(1.0f, d), e4.x - ek, MARGIN_F);
                bool p = (v > 0.0f) && (j > k); tot += p ? v : 0.0f; cnt += (int)__popcll(__ballot(p)); }
            {   const int j = j0 + jb + 1;
                float d = gk - g4.y; float v = fmaf(copysignf(1.0f, d), e4.y - ek, MARGIN_F);
                bool p = (v > 0.0f) && (j > k); tot += p ? v : 0.0f; cnt += (int)__popcll(__ballot(p)); }
            {   const int j = j0 + jb + 2;
                float d = gk - g4.z; float v = fmaf(copysignf(1.0f, d), e4.z - ek, MARGIN_F);
                bool p = (v > 0.0f) && (j > k); tot += p ? v : 0.0f; cnt += (int)__popcll(__ballot(p)); }
            {   const int j = j0 + jb + 3;
                float d = gk - g4.w; float v = fmaf(copysignf(1.0f, d), e4.w - ek, MARGIN_F);
                bool p = (v > 0.0f) && (j > k); tot += p ? v : 0.0f; cnt += (int)__popcll(__ballot(p)); }
        }
    }
    // lane reduce tot (cnt is wave-uniform via ballot); block reduce -> partial[b]
    for (int off = 32; off > 0; off >>= 1) tot += __shfl_down(tot, off, 64);
    if (lane == 0) { wt[wid] = tot; wc[wid] = cnt; }
    __syncthreads();
    if (t == 0) {
        float T = 0.0f; int C = 0;
        #pragma unroll
        for (int q = 0; q < TBLK / 64; ++q) { T += wt[q]; C += wc[q]; }
        partial[b] = make_float2(T, (float)C);
    }
    cg::this_grid().sync();

    // ---- Phase 3: block 0 reduces 256 partials -> out ----
    if (b == 0) {
        float T = 0.0f, C = 0.0f;
        if (t < GBLK) { float2 p = partial[t]; T = p.x; C = p.y; }
        for (int off = 32; off > 0; off >>= 1) {
            T += __shfl_down(T, off, 64);
            C += __shfl_down(C, off, 64);
        }
        if (lane == 0) { wt[wid] = T; wc[wid] = C; }
        __syncthreads();
        if (t == 0) {
            float Tt = 0.0f, Ct = 0.0f;
            #pragma unroll
            for (int q = 0; q < TBLK / 64; ++q) { Tt += wt[q]; Ct += wc[q]; }
            out[0] = (Ct > 0.0f) ? WEIGHT_F * Tt / Ct : 0.0f;
        }
    }
}

extern "C" void kernel_launch(void* const* d_in, const int* in_sizes, int n_in,
                              void* d_out, int out_size, void* d_ws, size_t ws_size,
                              hipStream_t stream) {
    const float* E  = (const float*)d_in[0];   // embeddings (320 x 129)
    const float* gt = (const float*)d_in[1];   // tree_distances (320 x 320)
    float* out = (float*)d_out;
    float2* partial = (float2*)d_ws;                      // 256 float2 = 2 KB
    float*  embp = (float*)((char*)d_ws + 4096);          // 320*320 f32 = 400 KB

    void* args[] = { (void*)&E, (void*)&gt, (void*)&embp, (void*)&partial, (void*)&out };
    hipLaunchCooperativeKernel((void*)coop_kernel, dim3(GBLK), dim3(TBLK), args, 0, stream);
}